// Round 7
// baseline (197.546 us; speedup 1.0000x reference)
//
#include <hip/hip_runtime.h>
#include <hip/hip_bf16.h>

#define CCH   512
#define BATCH 8
#define NPOS  1024
#define MQKV  1536
#define EPS   1e-5f
#define LOG2E 1.4426950408889634f

typedef __attribute__((ext_vector_type(4))) float f32x4;
typedef __attribute__((ext_vector_type(8))) __bf16 bf16x8;
typedef __attribute__((ext_vector_type(8))) unsigned short u16x8;
typedef __attribute__((ext_vector_type(4))) unsigned short u16x4;

__device__ inline unsigned short f2bf(float f) {
  __hip_bfloat16 h = __float2bfloat16(f);
  return __builtin_bit_cast(unsigned short, h);
}
__device__ inline float bf2f(unsigned short u) {
  return __bfloat162float(__builtin_bit_cast(__hip_bfloat16, u));
}

// LDS xor-swizzle (T2) on the READ side: ushort index within a [row][64] tile.
__device__ inline int sw(int row, int col) { return row * 64 + (col ^ ((row & 7) << 3)); }

// 16B async global->LDS. dst must be wave-uniform; HW scatters lane i at dst + i*16B.
__device__ inline void gload16(const void* g, void* l) {
  __builtin_amdgcn_global_load_lds((const __attribute__((address_space(1))) void*)g,
                                   (__attribute__((address_space(3))) void*)l, 16, 0, 0);
}

// ---------------- 1. weights fp32 -> bf16 (q rows pre-scaled by 0.125*log2e) ----------------
__global__ void prep_weights(const float* __restrict__ wq, const float* __restrict__ wo,
                             unsigned short* __restrict__ wqb, unsigned short* __restrict__ wob) {
  int i = blockIdx.x * 256 + threadIdx.x;
  if (i < MQKV * CCH) {
    float v = wq[i];
    if (i < 512 * CCH) v *= 0.125f * LOG2E;   // scores arrive in log2 domain
    wqb[i] = f2bf(v);
  }
  if (i < CCH * CCH) wob[i] = f2bf(wo[i]);
}

// ---------------- 2. CPB table: [8][63][63], scaled by log2e ----------------
__global__ void cpb_table(const float* __restrict__ w0, const float* __restrict__ b0,
                          const float* __restrict__ w1, const float* __restrict__ b1,
                          const float* __restrict__ w2, const float* __restrict__ b2,
                          float* __restrict__ table) {
  __shared__ float sh1[128];
  __shared__ float sh2[128];
  int d0 = blockIdx.x;               // 0..3968
  int dy = d0 / 63 - 31, dx = d0 % 63 - 31;
  float r0 = (dy > 0 ? 1.f : (dy < 0 ? -1.f : 0.f)) * logf(fabsf((float)dy) + 1.f);
  float r1 = (dx > 0 ? 1.f : (dx < 0 ? -1.f : 0.f)) * logf(fabsf((float)dx) + 1.f);
  int t = threadIdx.x;               // 128
  float h0 = r0 * w0[t * 2 + 0] + r1 * w0[t * 2 + 1] + b0[t];
  sh1[t] = (h0 >= 0.f) ? h0 : 0.1f * h0;
  __syncthreads();
  float a = b1[t];
  #pragma unroll 8
  for (int c = 0; c < 128; ++c) a += sh1[c] * w1[t * 128 + c];
  sh2[t] = (a >= 0.f) ? a : 0.1f * a;
  __syncthreads();
  if (t < 8) {
    float o = b2[t];
    #pragma unroll 8
    for (int c = 0; c < 128; ++c) o += sh2[c] * w2[t * 128 + c];
    table[t * 3969 + d0] = o * LOG2E;
  }
}

// ---------------- 3. expand bias, fragment-permuted: [h][i][jtile(16)][l16*4+jt] ----------------
__global__ void bias_expand(const float* __restrict__ table, unsigned short* __restrict__ biasP) {
  int idx = blockIdx.x * 256 + threadIdx.x;   // 8*1024*1024 total, idx == output address
  int h = idx >> 20;
  int i = (idx >> 10) & 1023;
  int blk = (idx >> 6) & 15;
  int q = idx & 63;
  int l16 = q >> 2, jt = q & 3;
  int j = blk * 64 + jt * 16 + l16;
  int dy = (i >> 5) - (j >> 5) + 31;
  int dx = (i & 31) - (j & 31) + 31;
  biasP[idx] = f2bf(table[h * 3969 + dy * 63 + dx]);
}

// ---------------- 4. channel LayerNorm -> xnT [8192][512] bf16 (coalesced) ----------------
__global__ __launch_bounds__(256) void ln_kernel(const float* __restrict__ x,
                                                 const float* __restrict__ gamma,
                                                 unsigned short* __restrict__ xnT) {
  __shared__ float red[4][32][2];
  __shared__ float gsh[512];
  __shared__ unsigned short obuf[32 * 520];
  int t = threadIdx.x;
  int blk = blockIdx.x;                        // 256 = 8 b * 32 pblocks
  int b = blk >> 5, p0 = (blk & 31) * 32;
  int pl = t & 31, wv = t >> 6, cg = t >> 5;   // cg 0..7
  gsh[t] = gamma[t];
  gsh[t + 256] = gamma[t + 256];
  const float* xp = x + (size_t)b * CCH * NPOS + p0 + pl;
  float vals[64];
  float s1 = 0.f, s2 = 0.f;
  #pragma unroll
  for (int j = 0; j < 64; ++j) {               // coalesced: 32 lanes x consecutive p
    float v = xp[(size_t)(cg + 8 * j) * NPOS];
    vals[j] = v; s1 += v; s2 += v * v;
  }
  s1 += __shfl_xor(s1, 32, 64); s2 += __shfl_xor(s2, 32, 64);
  if ((t & 63) < 32) { red[wv][pl][0] = s1; red[wv][pl][1] = s2; }
  __syncthreads();
  float t1 = 0.f, t2 = 0.f;
  #pragma unroll
  for (int w2 = 0; w2 < 4; ++w2) { t1 += red[w2][pl][0]; t2 += red[w2][pl][1]; }
  float mean = t1 * (1.f / 512.f);
  float var = t2 * (1.f / 512.f) - mean * mean;
  float rstd = rsqrtf(var + EPS);
  #pragma unroll
  for (int j = 0; j < 64; ++j) {
    int c = cg + 8 * j;
    obuf[pl * 520 + c] = f2bf((vals[j] - mean) * rstd * gsh[c]);
  }
  __syncthreads();
  unsigned short* orow = xnT + ((size_t)b * NPOS + p0) * 512;
  #pragma unroll
  for (int i = 0; i < 8; ++i) {
    int c2 = t + i * 256;
    int pp = c2 >> 6, ch = c2 & 63;
    *(u16x8*)&orow[(size_t)pp * 512 + ch * 8] = *(const u16x8*)&obuf[pp * 520 + ch * 8];
  }
}

// ---------------- 5. GEMM C = A * B^T, A[M][512], B[N][512] bf16 ----------------
template <int MODE>
__global__ __launch_bounds__(256) void gemm_bt(const unsigned short* __restrict__ Ag,
                                               const unsigned short* __restrict__ Bg,
                                               unsigned short* __restrict__ qT,
                                               unsigned short* __restrict__ kT,
                                               unsigned short* __restrict__ vB,
                                               const float* __restrict__ xres,
                                               float* __restrict__ yout) {
  __shared__ unsigned short smem[2 * 128 * 64];   // As | Bs; reused as 128x128 C-tile
  unsigned short* As = smem;
  unsigned short* Bs = smem + 128 * 64;
  int tid = threadIdx.x;
  int m0 = blockIdx.y * 128, nn0 = blockIdx.x * 128;
  int wave = tid >> 6, lane = tid & 63;
  int wm = wave >> 1, wn = wave & 1;
  int l16 = lane & 15, lh = lane >> 4;
  int rsub = lane >> 3, csub = lane & 7;
  int scsw = (csub ^ rsub) * 8;                   // pre-swizzled source col (ushorts)
  f32x4 acc[4][4];
  #pragma unroll
  for (int it = 0; it < 4; ++it)
    #pragma unroll
    for (int jt = 0; jt < 4; ++jt) acc[it][jt] = (f32x4){0.f, 0.f, 0.f, 0.f};

  for (int k0 = 0; k0 < 512; k0 += 64) {
    #pragma unroll
    for (int i = 0; i < 4; ++i) {
      int grp = wave * 4 + i;                     // 16 groups of 8 rows
      int row = grp * 8 + rsub;
      gload16(&Ag[(size_t)(m0 + row) * 512 + k0 + scsw], &As[grp * 512]);
      gload16(&Bg[(size_t)(nn0 + row) * 512 + k0 + scsw], &Bs[grp * 512]);
    }
    __syncthreads();
    #pragma unroll
    for (int ks = 0; ks < 2; ++ks) {
      int koff = ks * 32 + lh * 8;
      bf16x8 a[4], b[4];
      #pragma unroll
      for (int it = 0; it < 4; ++it) a[it] = *(const bf16x8*)&As[sw(wm * 64 + it * 16 + l16, koff)];
      #pragma unroll
      for (int jt = 0; jt < 4; ++jt) b[jt] = *(const bf16x8*)&Bs[sw(wn * 64 + jt * 16 + l16, koff)];
      #pragma unroll
      for (int it = 0; it < 4; ++it)
        #pragma unroll
        for (int jt = 0; jt < 4; ++jt)
          acc[it][jt] = __builtin_amdgcn_mfma_f32_16x16x32_bf16(a[it], b[jt], acc[it][jt], 0, 0, 0);
    }
    __syncthreads();
  }

  if (MODE == 1) {
    #pragma unroll
    for (int it = 0; it < 4; ++it) {
      int mbase = m0 + wm * 64 + it * 16 + lh * 4;
      #pragma unroll
      for (int jt = 0; jt < 4; ++jt) {
        int nn = nn0 + wn * 64 + jt * 16 + l16;
        int bb = nn >> 10, p = nn & 1023;
        #pragma unroll
        for (int r = 0; r < 4; ++r) {
          size_t addr = ((size_t)bb * 512 + mbase + r) * 1024 + p;
          yout[addr] = acc[it][jt][r] + xres[addr];
        }
      }
    }
  } else {
    // ---- LDS-bounced coalesced epilogue ----
    int by = blockIdx.y;
    int sel = by >> 2;                 // 0:q 1:k 2:v
    int hh0 = (by & 3) * 2;
    int bb = nn0 >> 10, p0 = nn0 & 1023;
    unsigned short* Cs = smem;         // 128x128 ushort = 32 KB
    if (sel < 2) {
      #pragma unroll
      for (int it = 0; it < 4; ++it)
        #pragma unroll
        for (int jt = 0; jt < 4; ++jt) {
          int nnl = wn * 64 + jt * 16 + l16;
          int mb = wm * 64 + it * 16 + lh * 4;
          #pragma unroll
          for (int r = 0; r < 4; ++r)
            Cs[nnl * 128 + ((mb + r) ^ ((nnl & 7) << 4))] = f2bf(acc[it][jt][r]);
        }
      __syncthreads();
      unsigned short* dst = (sel == 0) ? qT : kT;
      #pragma unroll
      for (int i = 0; i < 8; ++i) {
        int c = tid + i * 256;
        int hl = c >> 10, p = (c >> 3) & 127, ch = c & 7;
        int mb = hl * 64 + ch * 8;
        u16x8 val = *(u16x8*)&Cs[p * 128 + (mb ^ ((p & 7) << 4))];
        int bh = bb * 8 + hh0 + hl;
        *(u16x8*)&dst[((size_t)bh * 1024 + p0 + p) * 64 + ch * 8] = val;
      }
    } else {
      #pragma unroll
      for (int it = 0; it < 4; ++it)
        #pragma unroll
        for (int jt = 0; jt < 4; ++jt) {
          int nnl = wn * 64 + jt * 16 + l16;
          int mb = wm * 64 + it * 16 + lh * 4;
          #pragma unroll
          for (int r = 0; r < 4; ++r)
            Cs[(mb + r) * 128 + (nnl ^ (((mb + r) & 7) << 4))] = f2bf(acc[it][jt][r]);
        }
      __syncthreads();
      #pragma unroll
      for (int i = 0; i < 8; ++i) {
        int c = tid + i * 256;
        int mloc = c >> 4, ch = c & 15;
        u16x8 val = *(u16x8*)&Cs[mloc * 128 + ((ch * 8) ^ ((mloc & 7) << 4))];
        int d = mloc & 63, hl = mloc >> 6;
        int bh = bb * 8 + hh0 + hl;
        *(u16x8*)&vB[((size_t)bh * 64 + d) * 1024 + p0 + ch * 8] = val;
      }
    }
  }
}

// ---------------- 6. flash attention, NO-MAX softmax (un-normalized exp2, exact via
// ones-column denominator). K: gload_lds double-buffered. V+bias: register prefetch
// issued at tile start, consumed ~400cy later. No cross-lane ops, no cross-tile deps.
__global__ __launch_bounds__(256) void attn_kernel(const unsigned short* __restrict__ qT,
                                                   const unsigned short* __restrict__ kT,
                                                   const unsigned short* __restrict__ vB,
                                                   const unsigned short* __restrict__ biasP,
                                                   unsigned short* __restrict__ attnout) {
  __shared__ unsigned short Kbuf[2][64 * 64];
  __shared__ unsigned short Ps[4][16 * 64];
  int tid = threadIdx.x;
  int i0 = blockIdx.x * 64;          // i0-fastest grid (r3's proven config)
  int bh = blockIdx.y;
  int hh = bh & 7, bb = bh >> 3;
  int w = tid >> 6, lane = tid & 63, l16 = lane & 15, lh = lane >> 4;
  int rsub = lane >> 3, csub = lane & 7;
  int scsw = (csub ^ rsub) * 8;      // pre-swizzled source col

  const unsigned short* kbase = kT + (size_t)bh * NPOS * 64;
  const unsigned short* vrow  = vB + (size_t)bh * 64 * NPOS + l16 * 1024 + lh * 8;
  const unsigned short* bptr  = biasP + ((size_t)hh * 1024 + i0 + w * 16) * 1024 + l16 * 4;

  // Q fragments in registers (one q-row per lane)
  int qrow = i0 + w * 16 + l16;
  const unsigned short* qb = qT + ((size_t)bh * NPOS + qrow) * 64 + lh * 8;
  bf16x8 qreg[2];
  qreg[0] = *(const bf16x8*)&qb[0];
  qreg[1] = *(const bf16x8*)&qb[32];

  f32x4 o[5];                        // 0..3 output d-fragments, 4 = softmax denominator
  #pragma unroll
  for (int dt = 0; dt < 5; ++dt) o[dt] = (f32x4){0.f, 0.f, 0.f, 0.f};

  bf16x8 ones;
  {
    u16x8 tmp = {0x3F80, 0x3F80, 0x3F80, 0x3F80, 0x3F80, 0x3F80, 0x3F80, 0x3F80};
    ones = __builtin_bit_cast(bf16x8, tmp);
  }

  // stage K tile jj: 2 groups per wave, 1KB each
  #define STAGE_K(Kd, jj) do {                                                        \
    _Pragma("unroll")                                                                 \
    for (int i_ = 0; i_ < 2; ++i_) {                                                  \
      int grp_ = w * 2 + i_;                                                          \
      gload16(&kbase[(size_t)((jj) + grp_ * 8 + rsub) * 64 + scsw], &(Kd)[grp_ * 512]); \
    }                                                                                 \
  } while (0)

  STAGE_K(Kbuf[0], 0);
  __syncthreads();

  #pragma unroll 1
  for (int t = 0; t < 16; ++t) {
    int j0 = t * 64;

    // ---- prefetch V fragments + bias for THIS tile (consumed after QK^T) ----
    bf16x8 vv[2][4];
    #pragma unroll
    for (int js = 0; js < 2; ++js)
      #pragma unroll
      for (int dt = 0; dt < 4; ++dt)
        vv[js][dt] = *(const bf16x8*)&vrow[(size_t)(dt * 16) * 1024 + j0 + js * 32];
    u16x4 bv4[4];
    #pragma unroll
    for (int r = 0; r < 4; ++r) bv4[r] = *(const u16x4*)&bptr[(lh * 4 + r) * 1024 + j0];

    // ---- stage next K tile (in flight across compute, drained at barrier) ----
    if (t < 15) STAGE_K(Kbuf[(t + 1) & 1], j0 + 64);

    const unsigned short* Ks = Kbuf[t & 1];

    // ---- QK^T ----
    f32x4 s[4];
    #pragma unroll
    for (int jt = 0; jt < 4; ++jt) s[jt] = (f32x4){0.f, 0.f, 0.f, 0.f};
    #pragma unroll
    for (int ks = 0; ks < 2; ++ks) {
      int koff = ks * 32 + lh * 8;
      #pragma unroll
      for (int jt = 0; jt < 4; ++jt) {
        bf16x8 bk = *(const bf16x8*)&Ks[sw(jt * 16 + l16, koff)];
        s[jt] = __builtin_amdgcn_mfma_f32_16x16x32_bf16(qreg[ks], bk, s[jt], 0, 0, 0);
      }
    }

    // ---- elementwise softmax numerator: P = exp2(s + bias), no max, no reduce ----
    #pragma unroll
    for (int r = 0; r < 4; ++r) {
      int rloc = lh * 4 + r;
      #pragma unroll
      for (int jt = 0; jt < 4; ++jt) {
        float pv = __builtin_amdgcn_exp2f(s[jt][r] + bf2f(bv4[r][jt]));
        Ps[w][sw(rloc, jt * 16 + l16)] = f2bf(pv);
      }
    }

    // ---- PV (Ps wave-private: no barrier). o[4] accumulates the denominator ----
    #pragma unroll
    for (int js = 0; js < 2; ++js) {
      int koff = js * 32 + lh * 8;
      bf16x8 pa = *(const bf16x8*)&Ps[w][sw(l16, koff)];
      #pragma unroll
      for (int dt = 0; dt < 4; ++dt)
        o[dt] = __builtin_amdgcn_mfma_f32_16x16x32_bf16(pa, vv[js][dt], o[dt], 0, 0, 0);
      o[4] = __builtin_amdgcn_mfma_f32_16x16x32_bf16(pa, ones, o[4], 0, 0, 0);
    }

    // one barrier per tile: guards K buffer reuse AND drains next tile's staging
    __syncthreads();
  }

  #pragma unroll
  for (int r = 0; r < 4; ++r) {
    float inv = 1.f / o[4][r];
    int gi = i0 + w * 16 + lh * 4 + r;
    #pragma unroll
    for (int dt = 0; dt < 4; ++dt)
      attnout[((size_t)bb * 1024 + gi) * 512 + hh * 64 + dt * 16 + l16] = f2bf(o[dt][r] * inv);
  }
}

extern "C" void kernel_launch(void* const* d_in, const int* in_sizes, int n_in,
                              void* d_out, int out_size, void* d_ws, size_t ws_size,
                              hipStream_t stream) {
  const float* x     = (const float*)d_in[0];
  const float* gamma = (const float*)d_in[1];
  const float* w_qkv = (const float*)d_in[2];
  const float* w_out = (const float*)d_in[3];
  const float* cw0   = (const float*)d_in[4];
  const float* cb0   = (const float*)d_in[5];
  const float* cw1   = (const float*)d_in[6];
  const float* cb1   = (const float*)d_in[7];
  const float* cw2   = (const float*)d_in[8];
  const float* cb2   = (const float*)d_in[9];
  float* out = (float*)d_out;

  char* ws = (char*)d_ws;
  unsigned short* xnT   = (unsigned short*)(ws + 0);          // 8 MB
  unsigned short* wqb   = (unsigned short*)(ws + 8388608);    // 1.5 MB
  unsigned short* wob   = (unsigned short*)(ws + 9961472);    // 0.5 MB
  unsigned short* qT    = (unsigned short*)(ws + 10485760);   // 8 MB
  unsigned short* kT    = (unsigned short*)(ws + 18874368);   // 8 MB
  unsigned short* vB    = (unsigned short*)(ws + 27262976);   // 8 MB
  float*          table = (float*)(ws + 35651584);            // 128 KB
  unsigned short* biasP = (unsigned short*)(ws + 35782656);   // 16 MB
  unsigned short* aout  = (unsigned short*)(ws + 52559872);   // 8 MB

  prep_weights<<<3072, 256, 0, stream>>>(w_qkv, w_out, wqb, wob);
  cpb_table<<<3969, 128, 0, stream>>>(cw0, cb0, cw1, cb1, cw2, cb2, table);
  bias_expand<<<32768, 256, 0, stream>>>(table, biasP);
  ln_kernel<<<256, 256, 0, stream>>>(x, gamma, xnT);
  gemm_bt<0><<<dim3(64, 12), 256, 0, stream>>>(wqb, xnT, qT, kT, vB, nullptr, nullptr);
  attn_kernel<<<dim3(16, 64), 256, 0, stream>>>(qT, kT, vB, biasP, aout);
  gemm_bt<1><<<dim3(64, 4), 256, 0, stream>>>(wob, aout, nullptr, nullptr, nullptr, x, out);
}

// Round 8
// 147.791 us; speedup vs baseline: 1.3367x; 1.3367x over previous
//
#include <hip/hip_runtime.h>
#include <hip/hip_bf16.h>

#define CCH   512
#define BATCH 8
#define NPOS  1024
#define MQKV  1536
#define EPS   1e-5f
#define LOG2E 1.4426950408889634f

typedef __attribute__((ext_vector_type(4))) float f32x4;
typedef __attribute__((ext_vector_type(8))) __bf16 bf16x8;
typedef __attribute__((ext_vector_type(8))) unsigned short u16x8;
typedef __attribute__((ext_vector_type(4))) unsigned short u16x4;

__device__ inline unsigned short f2bf(float f) {
  __hip_bfloat16 h = __float2bfloat16(f);
  return __builtin_bit_cast(unsigned short, h);
}
__device__ inline float bf2f(unsigned short u) {
  return __bfloat162float(__builtin_bit_cast(__hip_bfloat16, u));
}

// LDS xor-swizzle (T2): ushort index within a [row][64] tile.
__device__ inline int sw(int row, int col) { return row * 64 + (col ^ ((row & 7) << 3)); }

// 16B async global->LDS (used by GEMM staging).
__device__ inline void gload16(const void* g, void* l) {
  __builtin_amdgcn_global_load_lds((const __attribute__((address_space(1))) void*)g,
                                   (__attribute__((address_space(3))) void*)l, 16, 0, 0);
}

// ---------------- 1. weights fp32 -> bf16 (q rows pre-scaled by 0.125*log2e) ----------------
__global__ void prep_weights(const float* __restrict__ wq, const float* __restrict__ wo,
                             unsigned short* __restrict__ wqb, unsigned short* __restrict__ wob) {
  int i = blockIdx.x * 256 + threadIdx.x;
  if (i < MQKV * CCH) {
    float v = wq[i];
    if (i < 512 * CCH) v *= 0.125f * LOG2E;   // scores arrive in log2 domain
    wqb[i] = f2bf(v);
  }
  if (i < CCH * CCH) wob[i] = f2bf(wo[i]);
}

// ---------------- 2. CPB table: [8][63][63], scaled by log2e ----------------
__global__ void cpb_table(const float* __restrict__ w0, const float* __restrict__ b0,
                          const float* __restrict__ w1, const float* __restrict__ b1,
                          const float* __restrict__ w2, const float* __restrict__ b2,
                          float* __restrict__ table) {
  __shared__ float sh1[128];
  __shared__ float sh2[128];
  int d0 = blockIdx.x;               // 0..3968
  int dy = d0 / 63 - 31, dx = d0 % 63 - 31;
  float r0 = (dy > 0 ? 1.f : (dy < 0 ? -1.f : 0.f)) * logf(fabsf((float)dy) + 1.f);
  float r1 = (dx > 0 ? 1.f : (dx < 0 ? -1.f : 0.f)) * logf(fabsf((float)dx) + 1.f);
  int t = threadIdx.x;               // 128
  float h0 = r0 * w0[t * 2 + 0] + r1 * w0[t * 2 + 1] + b0[t];
  sh1[t] = (h0 >= 0.f) ? h0 : 0.1f * h0;
  __syncthreads();
  float a = b1[t];
  #pragma unroll 8
  for (int c = 0; c < 128; ++c) a += sh1[c] * w1[t * 128 + c];
  sh2[t] = (a >= 0.f) ? a : 0.1f * a;
  __syncthreads();
  if (t < 8) {
    float o = b2[t];
    #pragma unroll 8
    for (int c = 0; c < 128; ++c) o += sh2[c] * w2[t * 128 + c];
    table[t * 3969 + d0] = o * LOG2E;
  }
}

// ---------------- 3. expand bias, fragment-permuted: [h][i][jtile(16)][l16*4+jt] ----------------
__global__ void bias_expand(const float* __restrict__ table, unsigned short* __restrict__ biasP) {
  int idx = blockIdx.x * 256 + threadIdx.x;   // 8*1024*1024 total, idx == output address
  int h = idx >> 20;
  int i = (idx >> 10) & 1023;
  int blk = (idx >> 6) & 15;
  int q = idx & 63;
  int l16 = q >> 2, jt = q & 3;
  int j = blk * 64 + jt * 16 + l16;
  int dy = (i >> 5) - (j >> 5) + 31;
  int dx = (i & 31) - (j & 31) + 31;
  biasP[idx] = f2bf(table[h * 3969 + dy * 63 + dx]);
}

// ---------------- 4. channel LayerNorm -> xnT [8192][512] bf16 (coalesced) ----------------
__global__ __launch_bounds__(256) void ln_kernel(const float* __restrict__ x,
                                                 const float* __restrict__ gamma,
                                                 unsigned short* __restrict__ xnT) {
  __shared__ float red[4][32][2];
  __shared__ float gsh[512];
  __shared__ unsigned short obuf[32 * 520];
  int t = threadIdx.x;
  int blk = blockIdx.x;                        // 256 = 8 b * 32 pblocks
  int b = blk >> 5, p0 = (blk & 31) * 32;
  int pl = t & 31, wv = t >> 6, cg = t >> 5;   // cg 0..7
  gsh[t] = gamma[t];
  gsh[t + 256] = gamma[t + 256];
  const float* xp = x + (size_t)b * CCH * NPOS + p0 + pl;
  float vals[64];
  float s1 = 0.f, s2 = 0.f;
  #pragma unroll
  for (int j = 0; j < 64; ++j) {               // coalesced: 32 lanes x consecutive p
    float v = xp[(size_t)(cg + 8 * j) * NPOS];
    vals[j] = v; s1 += v; s2 += v * v;
  }
  s1 += __shfl_xor(s1, 32, 64); s2 += __shfl_xor(s2, 32, 64);
  if ((t & 63) < 32) { red[wv][pl][0] = s1; red[wv][pl][1] = s2; }
  __syncthreads();
  float t1 = 0.f, t2 = 0.f;
  #pragma unroll
  for (int w2 = 0; w2 < 4; ++w2) { t1 += red[w2][pl][0]; t2 += red[w2][pl][1]; }
  float mean = t1 * (1.f / 512.f);
  float var = t2 * (1.f / 512.f) - mean * mean;
  float rstd = rsqrtf(var + EPS);
  #pragma unroll
  for (int j = 0; j < 64; ++j) {
    int c = cg + 8 * j;
    obuf[pl * 520 + c] = f2bf((vals[j] - mean) * rstd * gsh[c]);
  }
  __syncthreads();
  unsigned short* orow = xnT + ((size_t)b * NPOS + p0) * 512;
  #pragma unroll
  for (int i = 0; i < 8; ++i) {
    int c2 = t + i * 256;
    int pp = c2 >> 6, ch = c2 & 63;
    *(u16x8*)&orow[(size_t)pp * 512 + ch * 8] = *(const u16x8*)&obuf[pp * 520 + ch * 8];
  }
}

// ---------------- 5. GEMM C = A * B^T, A[M][512], B[N][512] bf16 ----------------
template <int MODE>
__global__ __launch_bounds__(256) void gemm_bt(const unsigned short* __restrict__ Ag,
                                               const unsigned short* __restrict__ Bg,
                                               unsigned short* __restrict__ qT,
                                               unsigned short* __restrict__ kT,
                                               unsigned short* __restrict__ vB,
                                               const float* __restrict__ xres,
                                               float* __restrict__ yout) {
  __shared__ unsigned short smem[2 * 128 * 64];   // As | Bs; reused as 128x128 C-tile
  unsigned short* As = smem;
  unsigned short* Bs = smem + 128 * 64;
  int tid = threadIdx.x;
  int m0 = blockIdx.y * 128, nn0 = blockIdx.x * 128;
  int wave = tid >> 6, lane = tid & 63;
  int wm = wave >> 1, wn = wave & 1;
  int l16 = lane & 15, lh = lane >> 4;
  int rsub = lane >> 3, csub = lane & 7;
  int scsw = (csub ^ rsub) * 8;                   // pre-swizzled source col (ushorts)
  f32x4 acc[4][4];
  #pragma unroll
  for (int it = 0; it < 4; ++it)
    #pragma unroll
    for (int jt = 0; jt < 4; ++jt) acc[it][jt] = (f32x4){0.f, 0.f, 0.f, 0.f};

  for (int k0 = 0; k0 < 512; k0 += 64) {
    #pragma unroll
    for (int i = 0; i < 4; ++i) {
      int grp = wave * 4 + i;                     // 16 groups of 8 rows
      int row = grp * 8 + rsub;
      gload16(&Ag[(size_t)(m0 + row) * 512 + k0 + scsw], &As[grp * 512]);
      gload16(&Bg[(size_t)(nn0 + row) * 512 + k0 + scsw], &Bs[grp * 512]);
    }
    __syncthreads();
    #pragma unroll
    for (int ks = 0; ks < 2; ++ks) {
      int koff = ks * 32 + lh * 8;
      bf16x8 a[4], b[4];
      #pragma unroll
      for (int it = 0; it < 4; ++it) a[it] = *(const bf16x8*)&As[sw(wm * 64 + it * 16 + l16, koff)];
      #pragma unroll
      for (int jt = 0; jt < 4; ++jt) b[jt] = *(const bf16x8*)&Bs[sw(wn * 64 + jt * 16 + l16, koff)];
      #pragma unroll
      for (int it = 0; it < 4; ++it)
        #pragma unroll
        for (int jt = 0; jt < 4; ++jt)
          acc[it][jt] = __builtin_amdgcn_mfma_f32_16x16x32_bf16(a[it], b[jt], acc[it][jt], 0, 0, 0);
    }
    __syncthreads();
  }

  if (MODE == 1) {
    #pragma unroll
    for (int it = 0; it < 4; ++it) {
      int mbase = m0 + wm * 64 + it * 16 + lh * 4;
      #pragma unroll
      for (int jt = 0; jt < 4; ++jt) {
        int nn = nn0 + wn * 64 + jt * 16 + l16;
        int bb = nn >> 10, p = nn & 1023;
        #pragma unroll
        for (int r = 0; r < 4; ++r) {
          size_t addr = ((size_t)bb * 512 + mbase + r) * 1024 + p;
          yout[addr] = acc[it][jt][r] + xres[addr];
        }
      }
    }
  } else {
    // ---- LDS-bounced coalesced epilogue ----
    int by = blockIdx.y;
    int sel = by >> 2;                 // 0:q 1:k 2:v
    int hh0 = (by & 3) * 2;
    int bb = nn0 >> 10, p0 = nn0 & 1023;
    unsigned short* Cs = smem;         // 128x128 ushort = 32 KB
    if (sel < 2) {
      #pragma unroll
      for (int it = 0; it < 4; ++it)
        #pragma unroll
        for (int jt = 0; jt < 4; ++jt) {
          int nnl = wn * 64 + jt * 16 + l16;
          int mb = wm * 64 + it * 16 + lh * 4;
          #pragma unroll
          for (int r = 0; r < 4; ++r)
            Cs[nnl * 128 + ((mb + r) ^ ((nnl & 7) << 4))] = f2bf(acc[it][jt][r]);
        }
      __syncthreads();
      unsigned short* dst = (sel == 0) ? qT : kT;
      #pragma unroll
      for (int i = 0; i < 8; ++i) {
        int c = tid + i * 256;
        int hl = c >> 10, p = (c >> 3) & 127, ch = c & 7;
        int mb = hl * 64 + ch * 8;
        u16x8 val = *(u16x8*)&Cs[p * 128 + (mb ^ ((p & 7) << 4))];
        int bh = bb * 8 + hh0 + hl;
        *(u16x8*)&dst[((size_t)bh * 1024 + p0 + p) * 64 + ch * 8] = val;
      }
    } else {
      #pragma unroll
      for (int it = 0; it < 4; ++it)
        #pragma unroll
        for (int jt = 0; jt < 4; ++jt) {
          int nnl = wn * 64 + jt * 16 + l16;
          int mb = wm * 64 + it * 16 + lh * 4;
          #pragma unroll
          for (int r = 0; r < 4; ++r)
            Cs[(mb + r) * 128 + (nnl ^ (((mb + r) & 7) << 4))] = f2bf(acc[it][jt][r]);
        }
      __syncthreads();
      #pragma unroll
      for (int i = 0; i < 8; ++i) {
        int c = tid + i * 256;
        int mloc = c >> 4, ch = c & 15;
        u16x8 val = *(u16x8*)&Cs[mloc * 128 + ((ch * 8) ^ ((mloc & 7) << 4))];
        int d = mloc & 63, hl = mloc >> 6;
        int bh = bb * 8 + hh0 + hl;
        *(u16x8*)&vB[((size_t)bh * 64 + d) * 1024 + p0 + ch * 8] = val;
      }
    }
  }
}

// ---------------- 6. flash attention: r3 cooperative-LDS skeleton + no-max softmax ----------------
// 64 q-rows/block, 4 waves, i0-fastest grid. K/V staged cooperatively (coalesced, once per
// block), single-buffered, 2 barriers/tile. Softmax = elementwise exp2 (no max, no reduce);
// denominator via ones-column PV accumulator (exact fp32 normalization).
__global__ __launch_bounds__(256) void attn_kernel(const unsigned short* __restrict__ qT,
                                                   const unsigned short* __restrict__ kT,
                                                   const unsigned short* __restrict__ vB,
                                                   const unsigned short* __restrict__ biasP,
                                                   unsigned short* __restrict__ attnout) {
  __shared__ unsigned short Ks[64 * 64];
  __shared__ unsigned short Vs[64 * 64];
  __shared__ unsigned short Ps[4][16 * 64];
  int tid = threadIdx.x;
  int i0 = blockIdx.x * 64;
  int bh = blockIdx.y;
  int hh = bh & 7, bb = bh >> 3;
  int w = tid >> 6, lane = tid & 63, l16 = lane & 15, lh = lane >> 4;

  const unsigned short* kbase = kT + (size_t)bh * NPOS * 64;
  const unsigned short* vbase = vB + (size_t)bh * 64 * NPOS;
  const unsigned short* bptr  = biasP + ((size_t)hh * 1024 + i0 + w * 16) * 1024 + l16 * 4;

  // Q fragments in registers (one q-row per lane)
  int qrow = i0 + w * 16 + l16;
  const unsigned short* qb = qT + ((size_t)bh * NPOS + qrow) * 64 + lh * 8;
  bf16x8 qreg[2];
  qreg[0] = *(const bf16x8*)&qb[0];
  qreg[1] = *(const bf16x8*)&qb[32];

  // staging geometry: 2048 ushorts per array; thread covers (row, col) and (row+32, col)
  int srow = tid >> 3, scol = (tid & 7) * 8;

  f32x4 o[5];                        // 0..3 output d-fragments, 4 = softmax denominator
  #pragma unroll
  for (int dt = 0; dt < 5; ++dt) o[dt] = (f32x4){0.f, 0.f, 0.f, 0.f};

  bf16x8 ones;
  {
    u16x8 tmp = {0x3F80, 0x3F80, 0x3F80, 0x3F80, 0x3F80, 0x3F80, 0x3F80, 0x3F80};
    ones = __builtin_bit_cast(bf16x8, tmp);
  }

  #pragma unroll 1
  for (int t = 0; t < 16; ++t) {
    int j0 = t * 64;
    // ---- cooperative staging: each byte loaded once, coalesced ----
    *(u16x8*)&Ks[sw(srow, scol)]      = *(const u16x8*)&kbase[(size_t)(j0 + srow) * 64 + scol];
    *(u16x8*)&Ks[sw(srow + 32, scol)] = *(const u16x8*)&kbase[(size_t)(j0 + srow + 32) * 64 + scol];
    *(u16x8*)&Vs[sw(srow, scol)]      = *(const u16x8*)&vbase[(size_t)srow * 1024 + j0 + scol];
    *(u16x8*)&Vs[sw(srow + 32, scol)] = *(const u16x8*)&vbase[(size_t)(srow + 32) * 1024 + j0 + scol];
    __syncthreads();

    // ---- bias preload (overlaps QK^T) ----
    u16x4 bv4[4];
    #pragma unroll
    for (int r = 0; r < 4; ++r) bv4[r] = *(const u16x4*)&bptr[(lh * 4 + r) * 1024 + j0];

    // ---- QK^T ----
    f32x4 s[4];
    #pragma unroll
    for (int jt = 0; jt < 4; ++jt) s[jt] = (f32x4){0.f, 0.f, 0.f, 0.f};
    #pragma unroll
    for (int ks = 0; ks < 2; ++ks) {
      int koff = ks * 32 + lh * 8;
      #pragma unroll
      for (int jt = 0; jt < 4; ++jt) {
        bf16x8 bk = *(const bf16x8*)&Ks[sw(jt * 16 + l16, koff)];
        s[jt] = __builtin_amdgcn_mfma_f32_16x16x32_bf16(qreg[ks], bk, s[jt], 0, 0, 0);
      }
    }

    // ---- elementwise softmax numerator: P = exp2(s + bias); no max, no cross-lane ----
    #pragma unroll
    for (int r = 0; r < 4; ++r) {
      int rloc = lh * 4 + r;
      #pragma unroll
      for (int jt = 0; jt < 4; ++jt) {
        float pv = __builtin_amdgcn_exp2f(s[jt][r] + bf2f(bv4[r][jt]));
        Ps[w][sw(rloc, jt * 16 + l16)] = f2bf(pv);
      }
    }

    // ---- PV (Ps wave-private: no barrier). o[4] accumulates the denominator ----
    #pragma unroll
    for (int js = 0; js < 2; ++js) {
      int koff = js * 32 + lh * 8;
      bf16x8 pa = *(const bf16x8*)&Ps[w][sw(l16, koff)];
      #pragma unroll
      for (int dt = 0; dt < 4; ++dt) {
        bf16x8 vb = *(const bf16x8*)&Vs[sw(dt * 16 + l16, koff)];
        o[dt] = __builtin_amdgcn_mfma_f32_16x16x32_bf16(pa, vb, o[dt], 0, 0, 0);
      }
      o[4] = __builtin_amdgcn_mfma_f32_16x16x32_bf16(pa, ones, o[4], 0, 0, 0);
    }
    __syncthreads();   // protect Ks/Vs before next tile's staging
  }

  #pragma unroll
  for (int r = 0; r < 4; ++r) {
    float inv = 1.f / o[4][r];
    int gi = i0 + w * 16 + lh * 4 + r;
    #pragma unroll
    for (int dt = 0; dt < 4; ++dt)
      attnout[((size_t)bb * 1024 + gi) * 512 + hh * 64 + dt * 16 + l16] = f2bf(o[dt][r] * inv);
  }
}

extern "C" void kernel_launch(void* const* d_in, const int* in_sizes, int n_in,
                              void* d_out, int out_size, void* d_ws, size_t ws_size,
                              hipStream_t stream) {
  const float* x     = (const float*)d_in[0];
  const float* gamma = (const float*)d_in[1];
  const float* w_qkv = (const float*)d_in[2];
  const float* w_out = (const float*)d_in[3];
  const float* cw0   = (const float*)d_in[4];
  const float* cb0   = (const float*)d_in[5];
  const float* cw1   = (const float*)d_in[6];
  const float* cb1   = (const float*)d_in[7];
  const float* cw2   = (const float*)d_in[8];
  const float* cb2   = (const float*)d_in[9];
  float* out = (float*)d_out;

  char* ws = (char*)d_ws;
  unsigned short* xnT   = (unsigned short*)(ws + 0);          // 8 MB
  unsigned short* wqb   = (unsigned short*)(ws + 8388608);    // 1.5 MB
  unsigned short* wob   = (unsigned short*)(ws + 9961472);    // 0.5 MB
  unsigned short* qT    = (unsigned short*)(ws + 10485760);   // 8 MB
  unsigned short* kT    = (unsigned short*)(ws + 18874368);   // 8 MB
  unsigned short* vB    = (unsigned short*)(ws + 27262976);   // 8 MB
  float*          table = (float*)(ws + 35651584);            // 128 KB
  unsigned short* biasP = (unsigned short*)(ws + 35782656);   // 16 MB
  unsigned short* aout  = (unsigned short*)(ws + 52559872);   // 8 MB

  prep_weights<<<3072, 256, 0, stream>>>(w_qkv, w_out, wqb, wob);
  cpb_table<<<3969, 128, 0, stream>>>(cw0, cb0, cw1, cb1, cw2, cb2, table);
  bias_expand<<<32768, 256, 0, stream>>>(table, biasP);
  ln_kernel<<<256, 256, 0, stream>>>(x, gamma, xnT);
  gemm_bt<0><<<dim3(64, 12), 256, 0, stream>>>(wqb, xnT, qT, kT, vB, nullptr, nullptr);
  attn_kernel<<<dim3(16, 64), 256, 0, stream>>>(qT, kT, vB, biasP, aout);
  gemm_bt<1><<<dim3(64, 4), 256, 0, stream>>>(wob, aout, nullptr, nullptr, nullptr, x, out);
}

// Round 9
// 145.908 us; speedup vs baseline: 1.3539x; 1.0129x over previous
//
#include <hip/hip_runtime.h>
#include <hip/hip_bf16.h>

#define CCH   512
#define BATCH 8
#define NPOS  1024
#define MQKV  1536
#define EPS   1e-5f
#define LOG2E 1.4426950408889634f

typedef __attribute__((ext_vector_type(4))) float f32x4;
typedef __attribute__((ext_vector_type(8))) __bf16 bf16x8;
typedef __attribute__((ext_vector_type(8))) unsigned short u16x8;
typedef __attribute__((ext_vector_type(4))) unsigned short u16x4;

__device__ inline unsigned short f2bf(float f) {
  __hip_bfloat16 h = __float2bfloat16(f);
  return __builtin_bit_cast(unsigned short, h);
}
__device__ inline float bf2f(unsigned short u) {
  return __bfloat162float(__builtin_bit_cast(__hip_bfloat16, u));
}

// LDS xor-swizzle (T2): ushort index within a [row][64] tile.
__device__ inline int sw(int row, int col) { return row * 64 + (col ^ ((row & 7) << 3)); }

// 16B async global->LDS. LDS dest is wave-uniform; HW scatters lane i at dst + i*16B.
__device__ inline void gload16(const void* g, void* l) {
  __builtin_amdgcn_global_load_lds((const __attribute__((address_space(1))) void*)g,
                                   (__attribute__((address_space(3))) void*)l, 16, 0, 0);
}

// ---------------- 1. weights fp32 -> bf16 (q rows pre-scaled by 0.125*log2e) ----------------
__global__ void prep_weights(const float* __restrict__ wq, const float* __restrict__ wo,
                             unsigned short* __restrict__ wqb, unsigned short* __restrict__ wob) {
  int i = blockIdx.x * 256 + threadIdx.x;
  if (i < MQKV * CCH) {
    float v = wq[i];
    if (i < 512 * CCH) v *= 0.125f * LOG2E;   // scores arrive in log2 domain
    wqb[i] = f2bf(v);
  }
  if (i < CCH * CCH) wob[i] = f2bf(wo[i]);
}

// ---------------- 2. CPB table: [8][63][63], scaled by log2e ----------------
__global__ void cpb_table(const float* __restrict__ w0, const float* __restrict__ b0,
                          const float* __restrict__ w1, const float* __restrict__ b1,
                          const float* __restrict__ w2, const float* __restrict__ b2,
                          float* __restrict__ table) {
  __shared__ float sh1[128];
  __shared__ float sh2[128];
  int d0 = blockIdx.x;               // 0..3968
  int dy = d0 / 63 - 31, dx = d0 % 63 - 31;
  float r0 = (dy > 0 ? 1.f : (dy < 0 ? -1.f : 0.f)) * logf(fabsf((float)dy) + 1.f);
  float r1 = (dx > 0 ? 1.f : (dx < 0 ? -1.f : 0.f)) * logf(fabsf((float)dx) + 1.f);
  int t = threadIdx.x;               // 128
  float h0 = r0 * w0[t * 2 + 0] + r1 * w0[t * 2 + 1] + b0[t];
  sh1[t] = (h0 >= 0.f) ? h0 : 0.1f * h0;
  __syncthreads();
  float a = b1[t];
  #pragma unroll 8
  for (int c = 0; c < 128; ++c) a += sh1[c] * w1[t * 128 + c];
  sh2[t] = (a >= 0.f) ? a : 0.1f * a;
  __syncthreads();
  if (t < 8) {
    float o = b2[t];
    #pragma unroll 8
    for (int c = 0; c < 128; ++c) o += sh2[c] * w2[t * 128 + c];
    table[t * 3969 + d0] = o * LOG2E;
  }
}

// ---------------- 3. expand bias, fragment-permuted: [h][i][jtile(16)][l16*4+jt] ----------------
__global__ void bias_expand(const float* __restrict__ table, unsigned short* __restrict__ biasP) {
  int idx = blockIdx.x * 256 + threadIdx.x;   // 8*1024*1024 total, idx == output address
  int h = idx >> 20;
  int i = (idx >> 10) & 1023;
  int blk = (idx >> 6) & 15;
  int q = idx & 63;
  int l16 = q >> 2, jt = q & 3;
  int j = blk * 64 + jt * 16 + l16;
  int dy = (i >> 5) - (j >> 5) + 31;
  int dx = (i & 31) - (j & 31) + 31;
  biasP[idx] = f2bf(table[h * 3969 + dy * 63 + dx]);
}

// ---------------- 4. channel LayerNorm -> xnT [8192][512] bf16 (coalesced) ----------------
__global__ __launch_bounds__(256) void ln_kernel(const float* __restrict__ x,
                                                 const float* __restrict__ gamma,
                                                 unsigned short* __restrict__ xnT) {
  __shared__ float red[4][32][2];
  __shared__ float gsh[512];
  __shared__ unsigned short obuf[32 * 520];
  int t = threadIdx.x;
  int blk = blockIdx.x;                        // 256 = 8 b * 32 pblocks
  int b = blk >> 5, p0 = (blk & 31) * 32;
  int pl = t & 31, wv = t >> 6, cg = t >> 5;   // cg 0..7
  gsh[t] = gamma[t];
  gsh[t + 256] = gamma[t + 256];
  const float* xp = x + (size_t)b * CCH * NPOS + p0 + pl;
  float vals[64];
  float s1 = 0.f, s2 = 0.f;
  #pragma unroll
  for (int j = 0; j < 64; ++j) {               // coalesced: 32 lanes x consecutive p
    float v = xp[(size_t)(cg + 8 * j) * NPOS];
    vals[j] = v; s1 += v; s2 += v * v;
  }
  s1 += __shfl_xor(s1, 32, 64); s2 += __shfl_xor(s2, 32, 64);
  if ((t & 63) < 32) { red[wv][pl][0] = s1; red[wv][pl][1] = s2; }
  __syncthreads();
  float t1 = 0.f, t2 = 0.f;
  #pragma unroll
  for (int w2 = 0; w2 < 4; ++w2) { t1 += red[w2][pl][0]; t2 += red[w2][pl][1]; }
  float mean = t1 * (1.f / 512.f);
  float var = t2 * (1.f / 512.f) - mean * mean;
  float rstd = rsqrtf(var + EPS);
  #pragma unroll
  for (int j = 0; j < 64; ++j) {
    int c = cg + 8 * j;
    obuf[pl * 520 + c] = f2bf((vals[j] - mean) * rstd * gsh[c]);
  }
  __syncthreads();
  unsigned short* orow = xnT + ((size_t)b * NPOS + p0) * 512;
  #pragma unroll
  for (int i = 0; i < 8; ++i) {
    int c2 = t + i * 256;
    int pp = c2 >> 6, ch = c2 & 63;
    *(u16x8*)&orow[(size_t)pp * 512 + ch * 8] = *(const u16x8*)&obuf[pp * 520 + ch * 8];
  }
}

// ---------------- 5. GEMM C = A * B^T, A[M][512], B[N][512] bf16 ----------------
template <int MODE>
__global__ __launch_bounds__(256) void gemm_bt(const unsigned short* __restrict__ Ag,
                                               const unsigned short* __restrict__ Bg,
                                               unsigned short* __restrict__ qT,
                                               unsigned short* __restrict__ kT,
                                               unsigned short* __restrict__ vB,
                                               const float* __restrict__ xres,
                                               float* __restrict__ yout) {
  __shared__ unsigned short smem[2 * 128 * 64];   // As | Bs; reused as 128x128 C-tile
  unsigned short* As = smem;
  unsigned short* Bs = smem + 128 * 64;
  int tid = threadIdx.x;
  int m0 = blockIdx.y * 128, nn0 = blockIdx.x * 128;
  int wave = tid >> 6, lane = tid & 63;
  int wm = wave >> 1, wn = wave & 1;
  int l16 = lane & 15, lh = lane >> 4;
  int rsub = lane >> 3, csub = lane & 7;
  int scsw = (csub ^ rsub) * 8;                   // pre-swizzled source col (ushorts)
  f32x4 acc[4][4];
  #pragma unroll
  for (int it = 0; it < 4; ++it)
    #pragma unroll
    for (int jt = 0; jt < 4; ++jt) acc[it][jt] = (f32x4){0.f, 0.f, 0.f, 0.f};

  for (int k0 = 0; k0 < 512; k0 += 64) {
    #pragma unroll
    for (int i = 0; i < 4; ++i) {
      int grp = wave * 4 + i;                     // 16 groups of 8 rows
      int row = grp * 8 + rsub;
      gload16(&Ag[(size_t)(m0 + row) * 512 + k0 + scsw], &As[grp * 512]);
      gload16(&Bg[(size_t)(nn0 + row) * 512 + k0 + scsw], &Bs[grp * 512]);
    }
    __syncthreads();
    #pragma unroll
    for (int ks = 0; ks < 2; ++ks) {
      int koff = ks * 32 + lh * 8;
      bf16x8 a[4], b[4];
      #pragma unroll
      for (int it = 0; it < 4; ++it) a[it] = *(const bf16x8*)&As[sw(wm * 64 + it * 16 + l16, koff)];
      #pragma unroll
      for (int jt = 0; jt < 4; ++jt) b[jt] = *(const bf16x8*)&Bs[sw(wn * 64 + jt * 16 + l16, koff)];
      #pragma unroll
      for (int it = 0; it < 4; ++it)
        #pragma unroll
        for (int jt = 0; jt < 4; ++jt)
          acc[it][jt] = __builtin_amdgcn_mfma_f32_16x16x32_bf16(a[it], b[jt], acc[it][jt], 0, 0, 0);
    }
    __syncthreads();
  }

  if (MODE == 1) {
    #pragma unroll
    for (int it = 0; it < 4; ++it) {
      int mbase = m0 + wm * 64 + it * 16 + lh * 4;
      #pragma unroll
      for (int jt = 0; jt < 4; ++jt) {
        int nn = nn0 + wn * 64 + jt * 16 + l16;
        int bb = nn >> 10, p = nn & 1023;
        #pragma unroll
        for (int r = 0; r < 4; ++r) {
          size_t addr = ((size_t)bb * 512 + mbase + r) * 1024 + p;
          yout[addr] = acc[it][jt][r] + xres[addr];
        }
      }
    }
  } else {
    // ---- LDS-bounced coalesced epilogue ----
    int by = blockIdx.y;
    int sel = by >> 2;                 // 0:q 1:k 2:v
    int hh0 = (by & 3) * 2;
    int bb = nn0 >> 10, p0 = nn0 & 1023;
    unsigned short* Cs = smem;         // 128x128 ushort = 32 KB
    if (sel < 2) {
      #pragma unroll
      for (int it = 0; it < 4; ++it)
        #pragma unroll
        for (int jt = 0; jt < 4; ++jt) {
          int nnl = wn * 64 + jt * 16 + l16;
          int mb = wm * 64 + it * 16 + lh * 4;
          #pragma unroll
          for (int r = 0; r < 4; ++r)
            Cs[nnl * 128 + ((mb + r) ^ ((nnl & 7) << 4))] = f2bf(acc[it][jt][r]);
        }
      __syncthreads();
      unsigned short* dst = (sel == 0) ? qT : kT;
      #pragma unroll
      for (int i = 0; i < 8; ++i) {
        int c = tid + i * 256;
        int hl = c >> 10, p = (c >> 3) & 127, ch = c & 7;
        int mb = hl * 64 + ch * 8;
        u16x8 val = *(u16x8*)&Cs[p * 128 + (mb ^ ((p & 7) << 4))];
        int bh = bb * 8 + hh0 + hl;
        *(u16x8*)&dst[((size_t)bh * 1024 + p0 + p) * 64 + ch * 8] = val;
      }
    } else {
      #pragma unroll
      for (int it = 0; it < 4; ++it)
        #pragma unroll
        for (int jt = 0; jt < 4; ++jt) {
          int nnl = wn * 64 + jt * 16 + l16;
          int mb = wm * 64 + it * 16 + lh * 4;
          #pragma unroll
          for (int r = 0; r < 4; ++r)
            Cs[(mb + r) * 128 + (nnl ^ (((mb + r) & 7) << 4))] = f2bf(acc[it][jt][r]);
        }
      __syncthreads();
      #pragma unroll
      for (int i = 0; i < 8; ++i) {
        int c = tid + i * 256;
        int mloc = c >> 4, ch = c & 15;
        u16x8 val = *(u16x8*)&Cs[mloc * 128 + ((ch * 8) ^ ((mloc & 7) << 4))];
        int d = mloc & 63, hl = mloc >> 6;
        int bh = bb * 8 + hh0 + hl;
        *(u16x8*)&vB[((size_t)bh * 64 + d) * 1024 + p0 + ch * 8] = val;
      }
    }
  }
}

// ---------------- 6. flash attention: r8 skeleton + gload_lds DOUBLE-buffered K/V ----------------
// 2-phase pipeline (T3-minimal): issue STAGE(t+1) before computing tile t; the single
// __syncthreads() per tile drains the in-flight staging (vmcnt) AND protects buffer reuse.
// No-max softmax (elementwise exp2); denominator via ones-column PV accumulator.
__global__ __launch_bounds__(256) void attn_kernel(const unsigned short* __restrict__ qT,
                                                   const unsigned short* __restrict__ kT,
                                                   const unsigned short* __restrict__ vB,
                                                   const unsigned short* __restrict__ biasP,
                                                   unsigned short* __restrict__ attnout) {
  __shared__ unsigned short Kbuf[2][64 * 64];
  __shared__ unsigned short Vbuf[2][64 * 64];
  __shared__ unsigned short Ps[4][16 * 64];
  int tid = threadIdx.x;
  int i0 = blockIdx.x * 64;          // i0-fastest grid (proven best)
  int bh = blockIdx.y;
  int hh = bh & 7, bb = bh >> 3;
  int w = tid >> 6, lane = tid & 63, l16 = lane & 15, lh = lane >> 4;
  int rsub = lane >> 3, csub = lane & 7;
  int scsw = (csub ^ rsub) * 8;      // pre-swizzled source col (both-sides rule, m173)

  const unsigned short* kbase = kT + (size_t)bh * NPOS * 64;
  const unsigned short* vbase = vB + (size_t)bh * 64 * NPOS;
  const unsigned short* bptr  = biasP + ((size_t)hh * 1024 + i0 + w * 16) * 1024 + l16 * 4;

  // Q fragments in registers (one q-row per lane)
  int qrow = i0 + w * 16 + l16;
  const unsigned short* qb = qT + ((size_t)bh * NPOS + qrow) * 64 + lh * 8;
  bf16x8 qreg[2];
  qreg[0] = *(const bf16x8*)&qb[0];
  qreg[1] = *(const bf16x8*)&qb[32];

  f32x4 o[5];                        // 0..3 output d-fragments, 4 = softmax denominator
  #pragma unroll
  for (int dt = 0; dt < 5; ++dt) o[dt] = (f32x4){0.f, 0.f, 0.f, 0.f};

  bf16x8 ones;
  {
    u16x8 tmp = {0x3F80, 0x3F80, 0x3F80, 0x3F80, 0x3F80, 0x3F80, 0x3F80, 0x3F80};
    ones = __builtin_bit_cast(bf16x8, tmp);
  }

  // stage tile jj into buffers Kd/Vd: per wave 2 K-groups + 2 V-groups, 1 KB each
  #define STAGE(Kd, Vd, jj) do {                                                          \
    _Pragma("unroll")                                                                     \
    for (int i_ = 0; i_ < 2; ++i_) {                                                      \
      int grp_ = w * 2 + i_;                                                              \
      gload16(&kbase[(size_t)((jj) + grp_ * 8 + rsub) * 64 + scsw], &(Kd)[grp_ * 512]);   \
      gload16(&vbase[(size_t)(grp_ * 8 + rsub) * 1024 + (jj) + scsw], &(Vd)[grp_ * 512]); \
    }                                                                                     \
  } while (0)

  STAGE(Kbuf[0], Vbuf[0], 0);
  __syncthreads();                   // drains prologue staging

  #pragma unroll 1
  for (int t = 0; t < 16; ++t) {
    int j0 = t * 64;
    // ---- issue next tile's staging first: in flight during this tile's compute ----
    if (t < 15) STAGE(Kbuf[(t + 1) & 1], Vbuf[(t + 1) & 1], j0 + 64);

    const unsigned short* Ks = Kbuf[t & 1];
    const unsigned short* Vs = Vbuf[t & 1];

    // ---- bias preload (overlaps QK^T) ----
    u16x4 bv4[4];
    #pragma unroll
    for (int r = 0; r < 4; ++r) bv4[r] = *(const u16x4*)&bptr[(lh * 4 + r) * 1024 + j0];

    // ---- QK^T ----
    f32x4 s[4];
    #pragma unroll
    for (int jt = 0; jt < 4; ++jt) s[jt] = (f32x4){0.f, 0.f, 0.f, 0.f};
    #pragma unroll
    for (int ks = 0; ks < 2; ++ks) {
      int koff = ks * 32 + lh * 8;
      #pragma unroll
      for (int jt = 0; jt < 4; ++jt) {
        bf16x8 bk = *(const bf16x8*)&Ks[sw(jt * 16 + l16, koff)];
        s[jt] = __builtin_amdgcn_mfma_f32_16x16x32_bf16(qreg[ks], bk, s[jt], 0, 0, 0);
      }
    }

    // ---- elementwise softmax numerator: P = exp2(s + bias); no max, no cross-lane ----
    #pragma unroll
    for (int r = 0; r < 4; ++r) {
      int rloc = lh * 4 + r;
      #pragma unroll
      for (int jt = 0; jt < 4; ++jt) {
        float pv = __builtin_amdgcn_exp2f(s[jt][r] + bf2f(bv4[r][jt]));
        Ps[w][sw(rloc, jt * 16 + l16)] = f2bf(pv);
      }
    }

    // ---- PV (Ps wave-private: no barrier). o[4] accumulates the denominator ----
    #pragma unroll
    for (int js = 0; js < 2; ++js) {
      int koff = js * 32 + lh * 8;
      bf16x8 pa = *(const bf16x8*)&Ps[w][sw(l16, koff)];
      #pragma unroll
      for (int dt = 0; dt < 4; ++dt) {
        bf16x8 vb = *(const bf16x8*)&Vs[sw(dt * 16 + l16, koff)];
        o[dt] = __builtin_amdgcn_mfma_f32_16x16x32_bf16(pa, vb, o[dt], 0, 0, 0);
      }
      o[4] = __builtin_amdgcn_mfma_f32_16x16x32_bf16(pa, ones, o[4], 0, 0, 0);
    }

    // single barrier per tile: drains next tile's staging + protects buffer reuse
    __syncthreads();
  }

  #pragma unroll
  for (int r = 0; r < 4; ++r) {
    float inv = 1.f / o[4][r];
    int gi = i0 + w * 16 + lh * 4 + r;
    #pragma unroll
    for (int dt = 0; dt < 4; ++dt)
      attnout[((size_t)bb * 1024 + gi) * 512 + hh * 64 + dt * 16 + l16] = f2bf(o[dt][r] * inv);
  }
}

extern "C" void kernel_launch(void* const* d_in, const int* in_sizes, int n_in,
                              void* d_out, int out_size, void* d_ws, size_t ws_size,
                              hipStream_t stream) {
  const float* x     = (const float*)d_in[0];
  const float* gamma = (const float*)d_in[1];
  const float* w_qkv = (const float*)d_in[2];
  const float* w_out = (const float*)d_in[3];
  const float* cw0   = (const float*)d_in[4];
  const float* cb0   = (const float*)d_in[5];
  const float* cw1   = (const float*)d_in[6];
  const float* cb1   = (const float*)d_in[7];
  const float* cw2   = (const float*)d_in[8];
  const float* cb2   = (const float*)d_in[9];
  float* out = (float*)d_out;

  char* ws = (char*)d_ws;
  unsigned short* xnT   = (unsigned short*)(ws + 0);          // 8 MB
  unsigned short* wqb   = (unsigned short*)(ws + 8388608);    // 1.5 MB
  unsigned short* wob   = (unsigned short*)(ws + 9961472);    // 0.5 MB
  unsigned short* qT    = (unsigned short*)(ws + 10485760);   // 8 MB
  unsigned short* kT    = (unsigned short*)(ws + 18874368);   // 8 MB
  unsigned short* vB    = (unsigned short*)(ws + 27262976);   // 8 MB
  float*          table = (float*)(ws + 35651584);            // 128 KB
  unsigned short* biasP = (unsigned short*)(ws + 35782656);   // 16 MB
  unsigned short* aout  = (unsigned short*)(ws + 52559872);   // 8 MB

  prep_weights<<<3072, 256, 0, stream>>>(w_qkv, w_out, wqb, wob);
  cpb_table<<<3969, 128, 0, stream>>>(cw0, cb0, cw1, cb1, cw2, cb2, table);
  bias_expand<<<32768, 256, 0, stream>>>(table, biasP);
  ln_kernel<<<256, 256, 0, stream>>>(x, gamma, xnT);
  gemm_bt<0><<<dim3(64, 12), 256, 0, stream>>>(wqb, xnT, qT, kT, vB, nullptr, nullptr);
  attn_kernel<<<dim3(16, 64), 256, 0, stream>>>(qT, kT, vB, biasP, aout);
  gemm_bt<1><<<dim3(64, 4), 256, 0, stream>>>(wob, aout, nullptr, nullptr, nullptr, x, out);
}